// Round 11
// baseline (2396.012 us; speedup 1.0000x reference)
//
#include <hip/hip_runtime.h>
#include <math.h>

#define H 512
#define V 5000
#define BB 128
#define SS 64
#define TT 52
#define NB 160   // persistent grid size

typedef __attribute__((ext_vector_type(8))) short bf16x8;
typedef __attribute__((ext_vector_type(4))) float f32x4;
typedef __attribute__((ext_vector_type(2))) float f32x2;

__device__ __forceinline__ unsigned short f2b(float f) {
    unsigned u = __float_as_uint(f);
    return (unsigned short)((u + 0x7fffu + ((u >> 16) & 1u)) >> 16);
}
__device__ __forceinline__ float b2f(unsigned short u) {
    return __uint_as_float((unsigned)u << 16);
}
__device__ __forceinline__ float ftanh(float x) {
    return 1.f - 2.f / (1.f + __expf(2.f * x));
}
__device__ __forceinline__ float fsig(float x) {
    return 1.f / (1.f + __expf(-x));
}
__device__ __forceinline__ unsigned char f2fp8(float f) {
    return (unsigned char)__builtin_amdgcn_cvt_pk_fp8_f32(f, f, 0, 0);
}

// ---------------------------------------------------------------------------
// Coherent (L1/L2-bypassing, L3-coherence-point) accesses; validated r4-r10.
// ---------------------------------------------------------------------------
#define CLD16_BODY \
        "global_load_dwordx4 %0, %16, off sc0 sc1\n\t"              \
        "global_load_dwordx4 %1, %16, off offset:64 sc0 sc1\n\t"    \
        "global_load_dwordx4 %2, %16, off offset:128 sc0 sc1\n\t"   \
        "global_load_dwordx4 %3, %16, off offset:192 sc0 sc1\n\t"   \
        "global_load_dwordx4 %4, %16, off offset:256 sc0 sc1\n\t"   \
        "global_load_dwordx4 %5, %16, off offset:320 sc0 sc1\n\t"   \
        "global_load_dwordx4 %6, %16, off offset:384 sc0 sc1\n\t"   \
        "global_load_dwordx4 %7, %16, off offset:448 sc0 sc1\n\t"   \
        "global_load_dwordx4 %8, %16, off offset:512 sc0 sc1\n\t"   \
        "global_load_dwordx4 %9, %16, off offset:576 sc0 sc1\n\t"   \
        "global_load_dwordx4 %10, %16, off offset:640 sc0 sc1\n\t"  \
        "global_load_dwordx4 %11, %16, off offset:704 sc0 sc1\n\t"  \
        "global_load_dwordx4 %12, %16, off offset:768 sc0 sc1\n\t"  \
        "global_load_dwordx4 %13, %16, off offset:832 sc0 sc1\n\t"  \
        "global_load_dwordx4 %14, %16, off offset:896 sc0 sc1\n\t"  \
        "global_load_dwordx4 %15, %16, off offset:960 sc0 sc1"
#define CLD16_OUTS(r) \
          "=v"(r[0]), "=v"(r[1]), "=v"(r[2]), "=v"(r[3]),   \
          "=v"(r[4]), "=v"(r[5]), "=v"(r[6]), "=v"(r[7]),   \
          "=v"(r[8]), "=v"(r[9]), "=v"(r[10]), "=v"(r[11]), \
          "=v"(r[12]), "=v"(r[13]), "=v"(r[14]), "=v"(r[15])

__device__ __forceinline__ void cld_row16_nw(const unsigned short* p, bf16x8* r)
{
    asm volatile(CLD16_BODY : CLD16_OUTS(r) : "v"(p) : "memory");
}
__device__ __forceinline__ void cld_row16(const unsigned short* p, bf16x8* r)
{
    asm volatile(CLD16_BODY "\n\ts_waitcnt vmcnt(0)"
                 : CLD16_OUTS(r) : "v"(p) : "memory");
}
__device__ __forceinline__ void cld_f_2(const float* p0, const float* p1,
                                        float& a, float& b)
{
    asm volatile(
        "global_load_dword %0, %2, off sc0 sc1\n\t"
        "global_load_dword %1, %3, off sc0 sc1\n\t"
        "s_waitcnt vmcnt(0)"
        : "=v"(a), "=v"(b) : "v"(p0), "v"(p1) : "memory");
}
// 8 strided scalar loads (stride 128 f32 = 512B), one base + imm offsets,
// single wait. For gathering Yt gate rows (column-major Yt).
__device__ __forceinline__ void cld_f8s(const float* p, float* r)
{
    asm volatile(
        "global_load_dword %0, %8, off sc0 sc1\n\t"
        "global_load_dword %1, %8, off offset:512 sc0 sc1\n\t"
        "global_load_dword %2, %8, off offset:1024 sc0 sc1\n\t"
        "global_load_dword %3, %8, off offset:1536 sc0 sc1\n\t"
        "global_load_dword %4, %8, off offset:2048 sc0 sc1\n\t"
        "global_load_dword %5, %8, off offset:2560 sc0 sc1\n\t"
        "global_load_dword %6, %8, off offset:3072 sc0 sc1\n\t"
        "global_load_dword %7, %8, off offset:3584 sc0 sc1\n\t"
        "s_waitcnt vmcnt(0)"
        : "=v"(r[0]), "=v"(r[1]), "=v"(r[2]), "=v"(r[3]),
          "=v"(r[4]), "=v"(r[5]), "=v"(r[6]), "=v"(r[7])
        : "v"(p) : "memory");
}
__device__ __forceinline__ void cst_f4(float* p, f32x4 v)
{
    asm volatile("global_store_dwordx4 %0, %1, off sc0 sc1"
                 :: "v"(p), "v"(v) : "memory");
}
__device__ __forceinline__ void cst_u32(unsigned* p, unsigned v)
{
    asm volatile("global_store_dword %0, %1, off sc0 sc1"
                 :: "v"(p), "v"(v) : "memory");
}
__device__ __forceinline__ void cst_h(unsigned short* p, unsigned short v)
{
    unsigned vv = v;
    asm volatile("global_store_short %0, %1, off sc0 sc1"
                 :: "v"(p), "v"(vv) : "memory");
}

// ---------------------------------------------------------------------------
// prep kernels (unchanged)
// ---------------------------------------------------------------------------
__global__ __launch_bounds__(256)
void prep_w(const float* __restrict__ Wa, const float* __restrict__ Whh,
            const float* __restrict__ Wih,
            const float* __restrict__ ba, const float* __restrict__ bih,
            const float* __restrict__ bhh,
            const float* __restrict__ Ua, const float* __restrict__ Wout,
            const float* __restrict__ enc,
            unsigned short* __restrict__ Wbig, unsigned short* __restrict__ Wc,
            unsigned short* __restrict__ Uab, unsigned short* __restrict__ Woutb,
            unsigned short* __restrict__ encb, float* __restrict__ bbig)
{
    const int stride = gridDim.x * blockDim.x;
    const int t0 = blockIdx.x * blockDim.x + threadIdx.x;
    for (int idx = t0; idx < 2560 * 1024; idx += stride) {
        const int j = idx >> 10, k = idx & 1023;
        float v;
        if (j < H) v = (k < H) ? Wa[j * H + k] : 0.f;
        else { const int n = j - H; v = (k < H) ? Whh[n * H + k] : Wih[n * 2 * H + (k - H)]; }
        Wbig[idx] = f2b(v);
    }
    for (int idx = t0; idx < 2048 * 512; idx += stride) {
        const int n = idx >> 9, k = idx & 511;
        Wc[idx] = f2b(Wih[n * 2 * H + H + k]);
    }
    for (int idx = t0; idx < 512 * 512; idx += stride)   Uab[idx]   = f2b(Ua[idx]);
    for (int idx = t0; idx < V * 512; idx += stride)     Woutb[idx] = f2b(Wout[idx]);
    for (int idx = t0; idx < BB * SS * H; idx += stride) encb[idx]  = f2b(enc[idx]);
    for (int j = t0; j < 2560; j += stride)
        bbig[j] = (j < H) ? ba[j] : bih[j - H] + bhh[j - H];
}

__global__ __launch_bounds__(256)
void gather_x(const float* __restrict__ emb, const int* __restrict__ tgt,
              unsigned short* __restrict__ xall)
{
    const int stride = gridDim.x * blockDim.x;
    for (int idx = blockIdx.x * blockDim.x + threadIdx.x; idx < TT * BB * H; idx += stride) {
        const int k = idx & 511;
        const int row = idx >> 9;
        const int t = row >> 7, b = row & 127;
        const int tok = (t == 0) ? 0 : tgt[b * TT + t - 1];
        xall[idx] = f2b(emb[(size_t)tok * H + k]);
    }
}

// ---------------------------------------------------------------------------
// bf16 MFMA NT-GEMM, K=512 fixed (keys + encW8 prep only now).
// ---------------------------------------------------------------------------
template<int OUT_MODE>
__global__ __launch_bounds__(256, 2)
void gemm_mfma(const unsigned short* __restrict__ A,
               const unsigned short* __restrict__ B,
               const float* __restrict__ bias,
               unsigned short* __restrict__ Cb,
               unsigned char* __restrict__ C8,
               int M, int N)
{
    __shared__ unsigned short As[128][72];
    __shared__ unsigned short Bs[128][72];
    const int tid = threadIdx.x;
    const int m0 = blockIdx.y * 128, n0 = blockIdx.x * 128;
    const int lane = tid & 63, wv = tid >> 6;
    const int qm = (wv >> 1) * 64, qn = (wv & 1) * 64;
    const int fr = lane & 15, fg = lane >> 4;
    f32x4 acc[4][4];
#pragma unroll
    for (int i = 0; i < 4; ++i)
#pragma unroll
        for (int j = 0; j < 4; ++j) acc[i][j] = (f32x4){0.f, 0.f, 0.f, 0.f};

    const int srow = tid >> 3, sc = (tid & 7) * 8;
    for (int k0 = 0; k0 < H; k0 += 64) {
#pragma unroll
        for (int u = 0; u < 4; ++u) {
            const int row = srow + u * 32;
            *(uint4*)&As[row][sc] = *(const uint4*)&A[(size_t)(m0 + row) * H + k0 + sc];
            int nr = n0 + row; if (nr > N - 1) nr = N - 1;
            *(uint4*)&Bs[row][sc] = *(const uint4*)&B[(size_t)nr * H + k0 + sc];
        }
        __syncthreads();
#pragma unroll
        for (int ks = 0; ks < 2; ++ks) {
            const int kk = ks * 32 + fg * 8;
            bf16x8 av[4], bv[4];
#pragma unroll
            for (int i = 0; i < 4; ++i) {
                av[i] = *(const bf16x8*)&As[qm + i * 16 + fr][kk];
                bv[i] = *(const bf16x8*)&Bs[qn + i * 16 + fr][kk];
            }
#pragma unroll
            for (int i = 0; i < 4; ++i)
#pragma unroll
                for (int j = 0; j < 4; ++j)
                    acc[i][j] = __builtin_amdgcn_mfma_f32_16x16x32_bf16(av[i], bv[j], acc[i][j], 0, 0, 0);
        }
        __syncthreads();
    }
#pragma unroll
    for (int i = 0; i < 4; ++i) {
        const int r0 = m0 + qm + i * 16 + fg * 4;
#pragma unroll
        for (int j = 0; j < 4; ++j) {
            const int col = n0 + qn + j * 16 + fr;
            if (col < N) {
                const float bi = bias ? bias[col] : 0.f;
#pragma unroll
                for (int v = 0; v < 4; ++v) {
                    const int r = r0 + v;
                    const float val = acc[i][j][v] + bi;
                    if (OUT_MODE == 1) Cb[(size_t)r * N + col] = f2b(val);
                    else               C8[(size_t)r * N + col] = f2fp8(val);
                }
            }
        }
    }
}

// ---------------------------------------------------------------------------
// Single-hop flags (round-9 scheme; replication was null in r10).
// ---------------------------------------------------------------------------
__device__ __forceinline__ void poll_ge(unsigned* a, unsigned step)
{
    if (__hip_atomic_load(a, __ATOMIC_RELAXED, __HIP_MEMORY_SCOPE_AGENT) >= step)
        return;
    do {
        __builtin_amdgcn_s_sleep(1);
    } while (__hip_atomic_load(a, __ATOMIC_RELAXED, __HIP_MEMORY_SCOPE_AGENT) < step);
}

struct PParams {
    const float* h0;
    const float* c0;
    const unsigned short* keysb;  // [B*S][512] bf16 (read-only, L2-cached)
    const unsigned char* encW8;   // [B*S][2048] fp8 (read-only, L2-resident)
    const float* Va;
    const float* bv;
    const float* bbig;
    const float* bout;
    const unsigned short* Wbig;   // [2560][1024] bf16
    const unsigned short* Woutb;  // [5000][512] bf16
    const unsigned short* xall;   // [T*B][512]   bf16 (read-only)
    unsigned short* hbf;          // [B][512] bf16     -- coherent
    float* Yt;                    // [2560][128] f32   -- coherent, COLUMN-major
    unsigned short* hallb;        // [T*B][512] bf16   -- coherent (logits reads)
    float* attn;                  // -> d_out attention block [B][T][S]
    float* out;                   // -> d_out logits [B][T][V]
    float* out_h;
    float* out_c;
    unsigned* pflag;              // [160*32]
    unsigned* qaflag;             // [32*32]
    unsigned* gateflag;           // [128*32]
    unsigned* hflag;              // [128*32]
};

// ---------------------------------------------------------------------------
// Persistent kernel. Blocks 128-159: qa cols (Yt rows 0-511) + fused LOGITS
// for step t-1 in their idle shadow. Blocks 0-127: gate cols (rows 512+16b)
// + P2 (attention, encW ctx-gates, LSTM). Yt column-major so P1's store
// drain before the signal is ~32 coalesced line transactions, not 512
// scattered scalars (round-6..10's hidden critical-path cost).
// ---------------------------------------------------------------------------
__global__ __launch_bounds__(256, 1)
void persist(PParams p)
{
    __shared__ unsigned short WA[16][1032];
    __shared__ float qa_s[H];
    __shared__ float va_s[H];
    __shared__ float part[SS][4];
    __shared__ float wbuf[SS];
    __shared__ float gbuf[4 * H];
    __shared__ float cs[H];

    const int tid  = threadIdx.x;
    const int beta = blockIdx.x;
    const int j0   = (beta < 128) ? (512 + beta * 16) : ((beta - 128) * 16);
    const int wv   = tid >> 6, lane = tid & 63;
    const int fr   = lane & 15, fg = lane >> 4;

    // ---- prologue ----
    for (int i = beta * 256 + tid; i < BB * H; i += NB * 256)
        cst_h(&p.hbf[i], f2b(p.h0[i]));
    for (int idx = tid; idx < 16 * 128; idx += 256) {
        const int r = idx >> 7, ch = idx & 127;
        *(uint4*)&WA[r][ch * 8] = *(const uint4*)&p.Wbig[(size_t)(j0 + r) * 1024 + ch * 8];
    }
    if (beta < 128) {
        for (int j = tid; j < H; j += 256) cs[j] = p.c0[beta * H + j];
        for (int i = tid; i < H; i += 256) va_s[i] = p.Va[i];
    }
    __syncthreads();
    if (tid == 0)
        __hip_atomic_store(&p.pflag[beta * 32], 1u, __ATOMIC_RELAXED,
                           __HIP_MEMORY_SCOPE_AGENT);
    for (int i = tid; i < NB; i += 256) poll_ge(&p.pflag[i * 32], 1u);
    __syncthreads();

    for (int t = 0; t < TT; ++t) {
        const unsigned st = (unsigned)(t + 1);
        // ---------------- P1: Yt rows j0..j0+15, all 128 batches ----------
        {
            const int r = fr, g = fg;
            const int b0 = wv * 32, b1 = b0 + 16;
            const int ko = g * 8;
            if (t > 0 && lane < 32)
                poll_ge(&p.hflag[(b0 + lane) * 32], (unsigned)t);
            bf16x8 hr0[16], hr1[16];
            cld_row16_nw(p.hbf + (size_t)(b0 + r) * H + ko, hr0);
            cld_row16  (p.hbf + (size_t)(b1 + r) * H + ko, hr1);
            __builtin_amdgcn_sched_barrier(0);   // MFMA hoist fence (rule #18)
            f32x4 acc0 = {0.f, 0.f, 0.f, 0.f};
            f32x4 acc1 = {0.f, 0.f, 0.f, 0.f};
#pragma unroll
            for (int ks = 0; ks < 16; ++ks) {
                bf16x8 bf = *(const bf16x8*)&WA[r][ks * 32 + ko];
                acc0 = __builtin_amdgcn_mfma_f32_16x16x32_bf16(hr0[ks], bf, acc0, 0, 0, 0);
                acc1 = __builtin_amdgcn_mfma_f32_16x16x32_bf16(hr1[ks], bf, acc1, 0, 0, 0);
            }
            const unsigned short* x0p = p.xall + ((size_t)t * BB + b0 + r) * H + ko;
            const unsigned short* x1p = p.xall + ((size_t)t * BB + b1 + r) * H + ko;
#pragma unroll
            for (int ks = 0; ks < 16; ++ks) {
                bf16x8 bf = *(const bf16x8*)&WA[r][512 + ks * 32 + ko];
                acc0 = __builtin_amdgcn_mfma_f32_16x16x32_bf16(*(const bf16x8*)&x0p[ks * 32], bf, acc0, 0, 0, 0);
                acc1 = __builtin_amdgcn_mfma_f32_16x16x32_bf16(*(const bf16x8*)&x1p[ks * 32], bf, acc1, 0, 0, 0);
            }
            const float bb = p.bbig[j0 + r];
            f32x4 o0, o1;
#pragma unroll
            for (int i = 0; i < 4; ++i) { o0[i] = acc0[i] + bb; o1[i] = acc1[i] + bb; }
            // coalesced column-major stores: row j0+r, batches b0+4g.. / b1+4g..
            cst_f4(p.Yt + (size_t)(j0 + r) * BB + b0 + g * 4, o0);
            cst_f4(p.Yt + (size_t)(j0 + r) * BB + b1 + g * 4, o1);
        }
        __syncthreads();   // drain (coalesced, fast)
        if (tid == 0) {
            if (beta < 128)
                __hip_atomic_store(&p.gateflag[beta * 32], st, __ATOMIC_RELAXED,
                                   __HIP_MEMORY_SCOPE_AGENT);
            else
                __hip_atomic_store(&p.qaflag[(beta - 128) * 32], st, __ATOMIC_RELAXED,
                                   __HIP_MEMORY_SCOPE_AGENT);
        }

        if (beta >= 128) {
            // ---------- fused logits for step t-1, in the idle shadow ------
            if (t > 0) {
                const int tl = t - 1;
                const int lb = beta - 128;
#pragma unroll
                for (int pass = 0; pass < 2; ++pass) {
                    const int nb = lb * 160 + pass * 80;
                    const int mg0 = 32 * wv, mg1 = mg0 + 16;
                    const unsigned short* A0 = p.hallb + ((size_t)tl * BB + mg0 + fr) * H;
                    const unsigned short* A1 = p.hallb + ((size_t)tl * BB + mg1 + fr) * H;
                    const unsigned short* Bp[5];
#pragma unroll
                    for (int cg = 0; cg < 5; ++cg) {
                        int nr = nb + cg * 16 + fr; if (nr > V - 1) nr = V - 1;
                        Bp[cg] = p.Woutb + (size_t)nr * H;
                    }
                    f32x4 acc[2][5];
#pragma unroll
                    for (int i = 0; i < 2; ++i)
#pragma unroll
                        for (int cg = 0; cg < 5; ++cg) acc[i][cg] = (f32x4){0.f, 0.f, 0.f, 0.f};
#pragma unroll
                    for (int ks = 0; ks < 16; ++ks) {
                        const int kk = ks * 32 + fg * 8;
                        bf16x8 a0 = *(const bf16x8*)&A0[kk];
                        bf16x8 a1 = *(const bf16x8*)&A1[kk];
#pragma unroll
                        for (int cg = 0; cg < 5; ++cg) {
                            bf16x8 bb = *(const bf16x8*)&Bp[cg][kk];
                            acc[0][cg] = __builtin_amdgcn_mfma_f32_16x16x32_bf16(a0, bb, acc[0][cg], 0, 0, 0);
                            acc[1][cg] = __builtin_amdgcn_mfma_f32_16x16x32_bf16(a1, bb, acc[1][cg], 0, 0, 0);
                        }
                    }
#pragma unroll
                    for (int i = 0; i < 2; ++i) {
                        const int mg = (i == 0) ? mg0 : mg1;
#pragma unroll
                        for (int cg = 0; cg < 5; ++cg) {
                            const int col = nb + cg * 16 + fr;
                            if (col < V) {
                                const float bo = p.bout[col];
#pragma unroll
                                for (int v = 0; v < 4; ++v) {
                                    const int bt = mg + fg * 4 + v;
                                    p.out[((size_t)bt * TT + tl) * V + col] = acc[i][cg][v] + bo;
                                }
                            }
                        }
                    }
                }
            }
        } else {
            // ------- P2: attention + ctx-gates + LSTM for batch b=beta -----
            const int b = beta;
            if (tid < 32) poll_ge(&p.qaflag[tid * 32], st);
            __syncthreads();
            cld_f_2(p.Yt + (size_t)tid * BB + b, p.Yt + (size_t)(tid + 256) * BB + b,
                    qa_s[tid], qa_s[tid + 256]);
            __syncthreads();
            // scores: vectorized keysb, 2-way ILP
            const int s = tid >> 2, q = tid & 3;
            const unsigned short* kp = p.keysb + ((size_t)b * SS + s) * H + q * 128;
            const float* qp = qa_s + q * 128;
            const float* vp = va_s + q * 128;
            float a2 = 0.f, a2b = 0.f;
#pragma unroll
            for (int i8 = 0; i8 < 16; ++i8) {
                bf16x8 kv = *(const bf16x8*)&kp[i8 * 8];
#pragma unroll
                for (int u = 0; u < 8; u += 2) {
                    const int i = i8 * 8 + u;
                    a2  += ftanh(qp[i]     + b2f((unsigned short)kv[u]))     * vp[i];
                    a2b += ftanh(qp[i + 1] + b2f((unsigned short)kv[u + 1])) * vp[i + 1];
                }
            }
            part[s][q] = a2 + a2b;
            __syncthreads();
            if (tid < 64) {
                float sc = part[tid][0] + part[tid][1] + part[tid][2] + part[tid][3] + p.bv[0];
                float m = sc;
                for (int o = 32; o; o >>= 1) m = fmaxf(m, __shfl_xor(m, o));
                const float e = __expf(sc - m);
                float ss = e;
                for (int o = 32; o; o >>= 1) ss += __shfl_xor(ss, o);
                const float w = e / ss;
                wbuf[tid] = w;
                p.attn[((size_t)b * TT + t) * SS + tid] = w;
            }
            if (tid < 128) poll_ge(&p.gateflag[tid * 32], st);
            __syncthreads();
            // gates: encW8 weighted sum + Yt gate rows (strided gather)
            {
                float gc[8] = {0.f, 0.f, 0.f, 0.f, 0.f, 0.f, 0.f, 0.f};
                const unsigned char* ew = p.encW8 + (size_t)b * SS * 2048 + tid * 8;
#pragma unroll 8
                for (int s2 = 0; s2 < SS; ++s2) {
                    const float w2 = wbuf[s2];
                    const uint2 u = *(const uint2*)(ew + (size_t)s2 * 2048);
                    const f32x2 e01 = __builtin_amdgcn_cvt_pk_f32_fp8(u.x, 0);
                    const f32x2 e23 = __builtin_amdgcn_cvt_pk_f32_fp8(u.x, 1);
                    const f32x2 e45 = __builtin_amdgcn_cvt_pk_f32_fp8(u.y, 0);
                    const f32x2 e67 = __builtin_amdgcn_cvt_pk_f32_fp8(u.y, 1);
                    gc[0] += w2 * e01[0]; gc[1] += w2 * e01[1];
                    gc[2] += w2 * e23[0]; gc[3] += w2 * e23[1];
                    gc[4] += w2 * e45[0]; gc[5] += w2 * e45[1];
                    gc[6] += w2 * e67[0]; gc[7] += w2 * e67[1];
                }
                float yg[8];
                cld_f8s(p.Yt + (size_t)(512 + tid * 8) * BB + b, yg);
#pragma unroll
                for (int i = 0; i < 8; ++i)
                    gbuf[tid * 8 + i] = gc[i] + yg[i];
            }
            __syncthreads();
            // LSTM: cells 2*tid, 2*tid+1
            {
                const int last = (t == TT - 1);
                unsigned hpack = 0;
                float hn2[2], cn2[2];
#pragma unroll
                for (int u = 0; u < 2; ++u) {
                    const int j = tid * 2 + u;
                    const float ig = gbuf[j];
                    const float fgt = gbuf[512 + j];
                    const float gg = gbuf[1024 + j];
                    const float og = gbuf[1536 + j];
                    const float co = cs[j];
                    const float cn = fsig(fgt) * co + fsig(ig) * ftanh(gg);
                    const float hn = fsig(og) * ftanh(cn);
                    cs[j] = cn;
                    hn2[u] = hn; cn2[u] = cn;
                    hpack |= ((unsigned)f2b(hn)) << (16 * u);
                }
                cst_u32((unsigned*)&p.hbf[b * H + tid * 2], hpack);
                cst_u32((unsigned*)&p.hallb[((size_t)t * BB + b) * H + tid * 2], hpack);
                if (last) {
#pragma unroll
                    for (int u = 0; u < 2; ++u) {
                        p.out_h[b * H + tid * 2 + u] = hn2[u];
                        p.out_c[b * H + tid * 2 + u] = cn2[u];
                    }
                }
            }
            __syncthreads();   // drain h stores
            if (tid == 0)
                __hip_atomic_store(&p.hflag[beta * 32], st, __ATOMIC_RELAXED,
                                   __HIP_MEMORY_SCOPE_AGENT);
        }
    }

    // -------- tail: logits for the final step (blocks 128-159) -----------
    if (beta >= 128) {
        for (int i = tid; i < 128; i += 256) poll_ge(&p.hflag[i * 32], (unsigned)TT);
        __syncthreads();
        const int tl = TT - 1;
        const int lb = beta - 128;
#pragma unroll
        for (int pass = 0; pass < 2; ++pass) {
            const int nb = lb * 160 + pass * 80;
            const int mg0 = 32 * wv, mg1 = mg0 + 16;
            const unsigned short* A0 = p.hallb + ((size_t)tl * BB + mg0 + fr) * H;
            const unsigned short* A1 = p.hallb + ((size_t)tl * BB + mg1 + fr) * H;
            const unsigned short* Bp[5];
#pragma unroll
            for (int cg = 0; cg < 5; ++cg) {
                int nr = nb + cg * 16 + fr; if (nr > V - 1) nr = V - 1;
                Bp[cg] = p.Woutb + (size_t)nr * H;
            }
            f32x4 acc[2][5];
#pragma unroll
            for (int i = 0; i < 2; ++i)
#pragma unroll
                for (int cg = 0; cg < 5; ++cg) acc[i][cg] = (f32x4){0.f, 0.f, 0.f, 0.f};
#pragma unroll
            for (int ks = 0; ks < 16; ++ks) {
                const int kk = ks * 32 + fg * 8;
                bf16x8 a0 = *(const bf16x8*)&A0[kk];
                bf16x8 a1 = *(const bf16x8*)&A1[kk];
#pragma unroll
                for (int cg = 0; cg < 5; ++cg) {
                    bf16x8 bb = *(const bf16x8*)&Bp[cg][kk];
                    acc[0][cg] = __builtin_amdgcn_mfma_f32_16x16x32_bf16(a0, bb, acc[0][cg], 0, 0, 0);
                    acc[1][cg] = __builtin_amdgcn_mfma_f32_16x16x32_bf16(a1, bb, acc[1][cg], 0, 0, 0);
                }
            }
#pragma unroll
            for (int i = 0; i < 2; ++i) {
                const int mg = (i == 0) ? mg0 : mg1;
#pragma unroll
                for (int cg = 0; cg < 5; ++cg) {
                    const int col = nb + cg * 16 + fr;
                    if (col < V) {
                        const float bo = p.bout[col];
#pragma unroll
                        for (int v = 0; v < 4; ++v) {
                            const int bt = mg + fg * 4 + v;
                            p.out[((size_t)bt * TT + tl) * V + col] = acc[i][cg][v] + bo;
                        }
                    }
                }
            }
        }
    }
}

// ---------------------------------------------------------------------------
// In-place log-softmax over each row of 5000 logits.
// ---------------------------------------------------------------------------
__global__ __launch_bounds__(256)
void logsoftmax_rows(float* __restrict__ P)
{
    __shared__ float red[256];
    float* p = P + (size_t)blockIdx.x * V;
    const int tid = threadIdx.x;
    float m = -1e30f;
    for (int i = tid; i < V; i += 256) m = fmaxf(m, p[i]);
    red[tid] = m; __syncthreads();
    for (int sft = 128; sft; sft >>= 1) {
        if (tid < sft) red[tid] = fmaxf(red[tid], red[tid + sft]);
        __syncthreads();
    }
    m = red[0]; __syncthreads();
    float ssum = 0.f;
    for (int i = tid; i < V; i += 256) ssum += __expf(p[i] - m);
    red[tid] = ssum; __syncthreads();
    for (int sft = 128; sft; sft >>= 1) {
        if (tid < sft) red[tid] += red[tid + sft];
        __syncthreads();
    }
    const float lse = m + __logf(red[0]);
    for (int i = tid; i < V; i += 256) p[i] -= lse;
}

// ---------------------------------------------------------------------------
extern "C" void kernel_launch(void* const* d_in, const int* in_sizes, int n_in,
                              void* d_out, int out_size, void* d_ws, size_t ws_size,
                              hipStream_t stream)
{
    (void)in_sizes; (void)n_in; (void)out_size; (void)ws_size;
    const float* enc  = (const float*)d_in[0];
    const float* h0   = (const float*)d_in[1];
    const float* c0   = (const float*)d_in[2];
    const int*   tgt  = (const int*)  d_in[3];
    const float* emb  = (const float*)d_in[4];
    const float* Wa   = (const float*)d_in[5];
    const float* ba   = (const float*)d_in[6];
    const float* Ua   = (const float*)d_in[7];
    const float* bu   = (const float*)d_in[8];
    const float* Va   = (const float*)d_in[9];
    const float* bv   = (const float*)d_in[10];
    const float* Wih  = (const float*)d_in[11];
    const float* Whh  = (const float*)d_in[12];
    const float* bih  = (const float*)d_in[13];
    const float* bhh  = (const float*)d_in[14];
    const float* Wout = (const float*)d_in[15];
    const float* bout = (const float*)d_in[16];

    float* ws = (float*)d_ws;
    float* Yt   = ws;                                      // 327,680 f32
    float* bbig = Yt + 327680;                             // 2,560 f32
    unsigned* flags = (unsigned*)(bbig + 2560);            // 14,336 u32
    unsigned* pflag    = flags;                            // 160*32
    unsigned* qaflag   = flags + 5120;                     // 32*32
    unsigned* gateflag = flags + 6144;                     // 128*32
    unsigned* hflag    = flags + 10240;                    // 128*32
    unsigned short* Wbig  = (unsigned short*)(flags + 14336);  // 2,621,440 u16
    unsigned short* Wc    = Wbig + 2621440;                // 1,048,576
    unsigned short* Uab   = Wc + 1048576;                  // 262,144
    unsigned short* Woutb = Uab + 262144;                  // 2,560,000
    unsigned short* encb  = Woutb + 2560000;               // 4,194,304
    unsigned short* keysb = encb + 4194304;                // 4,194,304
    unsigned short* xall  = keysb + 4194304;               // 3,407,872
    unsigned short* hallb = xall + 3407872;                // 3,407,872
    unsigned short* hbf   = hallb + 3407872;               // 65,536
    unsigned char*  encW8 = (unsigned char*)(hbf + 65536); // 16,777,216 u8

    float* out    = (float*)d_out;
    float* out_h  = out + (size_t)BB * TT * V;
    float* out_c  = out_h + BB * H;
    float* out_at = out_c + BB * H;

    hipMemsetAsync(flags, 0, 14336 * sizeof(unsigned), stream);

    prep_w<<<dim3(2048), dim3(256), 0, stream>>>(
        Wa, Whh, Wih, ba, bih, bhh, Ua, Wout, enc, Wbig, Wc, Uab, Woutb, encb, bbig);
    gather_x<<<dim3(512), dim3(256), 0, stream>>>(emb, tgt, xall);

    // keys_proj = enc @ Ua^T + bu  -> bf16 [8192,512]
    gemm_mfma<1><<<dim3(4, 64), dim3(256), 0, stream>>>(
        encb, Uab, bu, keysb, nullptr, BB * SS, H);
    // encW8 = enc @ Wc^T -> fp8 [8192,2048]  (L2-resident per-XCD slices)
    gemm_mfma<2><<<dim3(16, 64), dim3(256), 0, stream>>>(
        encb, Wc, nullptr, nullptr, encW8, BB * SS, 2048);

    PParams pp;
    pp.h0 = h0; pp.c0 = c0; pp.keysb = keysb; pp.encW8 = encW8;
    pp.Va = Va; pp.bv = bv; pp.bbig = bbig; pp.bout = bout;
    pp.Wbig = Wbig; pp.Woutb = Woutb; pp.xall = xall;
    pp.hbf = hbf; pp.Yt = Yt; pp.hallb = hallb;
    pp.attn = out_at; pp.out = out; pp.out_h = out_h; pp.out_c = out_c;
    pp.pflag = pflag; pp.qaflag = qaflag; pp.gateflag = gateflag; pp.hflag = hflag;
    persist<<<dim3(NB), dim3(256), 0, stream>>>(pp);

    logsoftmax_rows<<<dim3(BB * TT), dim3(256), 0, stream>>>(out);
}

// Round 14
// 1272.987 us; speedup vs baseline: 1.8822x; 1.8822x over previous
//
#include <hip/hip_runtime.h>
#include <math.h>

#define H 512
#define V 5000
#define BB 128
#define SS 64
#define TT 52
#define GSZ 16      // blocks per group = batches per group
#define NBLK 128    // persistent blocks (co-residency proven at 160)
#define LROWS 96    // weight rows LDS-staged per block (of 160)

typedef __attribute__((ext_vector_type(8))) short bf16x8;
typedef __attribute__((ext_vector_type(4))) float f32x4;
typedef __attribute__((ext_vector_type(2))) float f32x2;

__device__ __forceinline__ unsigned short f2b(float f) {
    unsigned u = __float_as_uint(f);
    return (unsigned short)((u + 0x7fffu + ((u >> 16) & 1u)) >> 16);
}
__device__ __forceinline__ float b2f(unsigned short u) {
    return __uint_as_float((unsigned)u << 16);
}
__device__ __forceinline__ float ftanh(float x) {
    return 1.f - 2.f / (1.f + __expf(2.f * x));
}
__device__ __forceinline__ float fsig(float x) {
    return 1.f / (1.f + __expf(-x));
}
__device__ __forceinline__ unsigned char f2fp8(float f) {
    return (unsigned char)__builtin_amdgcn_cvt_pk_fp8_f32(f, f, 0, 0);
}

// ---------------------------------------------------------------------------
// Cross-block coherent accesses: sc0 sc1 ONLY (L3 coherence point; proven
// r4-r10). LESSON r12/r13: sc0-only loads do NOT bypass L1 on gfx950 ->
// pollers spin on stale L1 lines forever. Never use sc0-only across blocks.
// ---------------------------------------------------------------------------
__device__ __forceinline__ void pollf(unsigned* a, unsigned s)
{
    for (;;) {
        unsigned v;
        asm volatile("global_load_dword %0, %1, off sc0 sc1\n\ts_waitcnt vmcnt(0)"
                     : "=v"(v) : "v"(a) : "memory");
        if (v >= s) break;
        __builtin_amdgcn_s_sleep(1);
    }
}
__device__ __forceinline__ void fst(unsigned* p, unsigned v)
{
    asm volatile("global_store_dword %0, %1, off sc0 sc1" :: "v"(p), "v"(v) : "memory");
}
__device__ __forceinline__ void cstf4(float* p, f32x4 v)
{
    asm volatile("global_store_dwordx4 %0, %1, off sc0 sc1" :: "v"(p), "v"(v) : "memory");
}
__device__ __forceinline__ void cld4x16B(const unsigned short* p0, const unsigned short* p1,
                                         const unsigned short* p2, const unsigned short* p3,
                                         uint4& a, uint4& b, uint4& c, uint4& d)
{
    asm volatile(
        "global_load_dwordx4 %0, %4, off sc0 sc1\n\t"
        "global_load_dwordx4 %1, %5, off sc0 sc1\n\t"
        "global_load_dwordx4 %2, %6, off sc0 sc1\n\t"
        "global_load_dwordx4 %3, %7, off sc0 sc1\n\t"
        "s_waitcnt vmcnt(0)"
        : "=v"(a), "=v"(b), "=v"(c), "=v"(d)
        : "v"(p0), "v"(p1), "v"(p2), "v"(p3) : "memory");
}
__device__ __forceinline__ void cldf2(const float* p0, const float* p1, float& a, float& b)
{
    asm volatile(
        "global_load_dword %0, %2, off sc0 sc1\n\t"
        "global_load_dword %1, %3, off sc0 sc1\n\t"
        "s_waitcnt vmcnt(0)"
        : "=v"(a), "=v"(b) : "v"(p0), "v"(p1) : "memory");
}
// 8 strided f32 loads (stride GSZ f32 = 64B), one wait (Ybuf gate rows).
__device__ __forceinline__ void cldf8s(const float* p, float* r)
{
    asm volatile(
        "global_load_dword %0, %8, off sc0 sc1\n\t"
        "global_load_dword %1, %8, off offset:64 sc0 sc1\n\t"
        "global_load_dword %2, %8, off offset:128 sc0 sc1\n\t"
        "global_load_dword %3, %8, off offset:192 sc0 sc1\n\t"
        "global_load_dword %4, %8, off offset:256 sc0 sc1\n\t"
        "global_load_dword %5, %8, off offset:320 sc0 sc1\n\t"
        "global_load_dword %6, %8, off offset:384 sc0 sc1\n\t"
        "global_load_dword %7, %8, off offset:448 sc0 sc1\n\t"
        "s_waitcnt vmcnt(0)"
        : "=v"(r[0]), "=v"(r[1]), "=v"(r[2]), "=v"(r[3]),
          "=v"(r[4]), "=v"(r[5]), "=v"(r[6]), "=v"(r[7])
        : "v"(p) : "memory");
}
__device__ __forceinline__ void cstu32c(unsigned* p, unsigned v)
{
    asm volatile("global_store_dword %0, %1, off sc0 sc1" :: "v"(p), "v"(v) : "memory");
}

// ---------------------------------------------------------------------------
// prep: Whb [2560][512] = [Wa ; W_hh], Wxb [2048][512] = W_ih[:, :512],
// Wc [2048][512] = W_ih[:, 512:], bbig = [ba ; b_ih+b_hh], bf16 Ua/Wout/enc.
// ---------------------------------------------------------------------------
__global__ __launch_bounds__(256)
void prep_w(const float* __restrict__ Wa, const float* __restrict__ Whh,
            const float* __restrict__ Wih,
            const float* __restrict__ ba, const float* __restrict__ bih,
            const float* __restrict__ bhh,
            const float* __restrict__ Ua, const float* __restrict__ Wout,
            const float* __restrict__ enc,
            unsigned short* __restrict__ Whb, unsigned short* __restrict__ Wxb,
            unsigned short* __restrict__ Wc,
            unsigned short* __restrict__ Uab, unsigned short* __restrict__ Woutb,
            unsigned short* __restrict__ encb, float* __restrict__ bbig)
{
    const int stride = gridDim.x * blockDim.x;
    const int t0 = blockIdx.x * blockDim.x + threadIdx.x;
    for (int idx = t0; idx < 2560 * 512; idx += stride) {
        const int j = idx >> 9, k = idx & 511;
        Whb[idx] = f2b((j < H) ? Wa[j * H + k] : Whh[(j - H) * H + k]);
    }
    for (int idx = t0; idx < 2048 * 512; idx += stride) {
        const int n = idx >> 9, k = idx & 511;
        Wxb[idx] = f2b(Wih[n * 2 * H + k]);
        Wc[idx]  = f2b(Wih[n * 2 * H + H + k]);
    }
    for (int idx = t0; idx < 512 * 512; idx += stride)   Uab[idx]   = f2b(Ua[idx]);
    for (int idx = t0; idx < V * 512; idx += stride)     Woutb[idx] = f2b(Wout[idx]);
    for (int idx = t0; idx < BB * SS * H; idx += stride) encb[idx]  = f2b(enc[idx]);
    for (int j = t0; j < 2560; j += stride)
        bbig[j] = (j < H) ? ba[j] : bih[j - H] + bhh[j - H];
}

__global__ __launch_bounds__(256)
void gather_x(const float* __restrict__ emb, const int* __restrict__ tgt,
              unsigned short* __restrict__ xall)
{
    const int stride = gridDim.x * blockDim.x;
    for (int idx = blockIdx.x * blockDim.x + threadIdx.x; idx < TT * BB * H; idx += stride) {
        const int k = idx & 511;
        const int row = idx >> 9;
        const int t = row >> 7, b = row & 127;
        const int tok = (t == 0) ? 0 : tgt[b * TT + t - 1];
        xall[idx] = f2b(emb[(size_t)tok * H + k]);
    }
}

// ---------------------------------------------------------------------------
// bf16 MFMA NT-GEMM, K=512. OUT_MODE: 0=f32 (+PERMUTE r=t*B+b -> b*T+t),
// 1=bf16, 2=fp8. Used for keysb, encW8, xgates, logits.
// ---------------------------------------------------------------------------
template<int OUT_MODE, int PERMUTE>
__global__ __launch_bounds__(256, 2)
void gemm_mfma(const unsigned short* __restrict__ A,
               const unsigned short* __restrict__ B,
               const float* __restrict__ bias,
               float* __restrict__ Cf, unsigned short* __restrict__ Cb,
               unsigned char* __restrict__ C8,
               int M, int N)
{
    __shared__ unsigned short As[128][72];
    __shared__ unsigned short Bs[128][72];
    const int tid = threadIdx.x;
    const int m0 = blockIdx.y * 128, n0 = blockIdx.x * 128;
    const int lane = tid & 63, wv = tid >> 6;
    const int qm = (wv >> 1) * 64, qn = (wv & 1) * 64;
    const int fr = lane & 15, fg = lane >> 4;
    f32x4 acc[4][4];
#pragma unroll
    for (int i = 0; i < 4; ++i)
#pragma unroll
        for (int j = 0; j < 4; ++j) acc[i][j] = (f32x4){0.f, 0.f, 0.f, 0.f};

    const int srow = tid >> 3, sc = (tid & 7) * 8;
    for (int k0 = 0; k0 < H; k0 += 64) {
#pragma unroll
        for (int u = 0; u < 4; ++u) {
            const int row = srow + u * 32;
            *(uint4*)&As[row][sc] = *(const uint4*)&A[(size_t)(m0 + row) * H + k0 + sc];
            int nr = n0 + row; if (nr > N - 1) nr = N - 1;
            *(uint4*)&Bs[row][sc] = *(const uint4*)&B[(size_t)nr * H + k0 + sc];
        }
        __syncthreads();
#pragma unroll
        for (int ks = 0; ks < 2; ++ks) {
            const int kk = ks * 32 + fg * 8;
            bf16x8 av[4], bv[4];
#pragma unroll
            for (int i = 0; i < 4; ++i) {
                av[i] = *(const bf16x8*)&As[qm + i * 16 + fr][kk];
                bv[i] = *(const bf16x8*)&Bs[qn + i * 16 + fr][kk];
            }
#pragma unroll
            for (int i = 0; i < 4; ++i)
#pragma unroll
                for (int j = 0; j < 4; ++j)
                    acc[i][j] = __builtin_amdgcn_mfma_f32_16x16x32_bf16(av[i], bv[j], acc[i][j], 0, 0, 0);
        }
        __syncthreads();
    }
#pragma unroll
    for (int i = 0; i < 4; ++i) {
        const int r0 = m0 + qm + i * 16 + fg * 4;
#pragma unroll
        for (int j = 0; j < 4; ++j) {
            const int col = n0 + qn + j * 16 + fr;
            if (col < N) {
                const float bi = bias ? bias[col] : 0.f;
#pragma unroll
                for (int v = 0; v < 4; ++v) {
                    const int r = r0 + v;
                    const float val = acc[i][j][v] + bi;
                    if (OUT_MODE == 1) Cb[(size_t)r * N + col] = f2b(val);
                    else if (OUT_MODE == 2) C8[(size_t)r * N + col] = f2fp8(val);
                    else {
                        const size_t orow = PERMUTE ? ((size_t)(r & (BB - 1)) * TT + (r >> 7))
                                                    : (size_t)r;
                        Cf[orow * (size_t)N + col] = val;
                    }
                }
            }
        }
    }
}

struct PParams {
    const float* h0;
    const float* c0;
    const unsigned short* keysb;   // [B*S][512] bf16 (plain cached)
    const unsigned char* encW8;    // [B*S][2048] fp8 (plain cached)
    const float* Va;
    const float* bv;
    const float* bbig;             // [2560]
    const unsigned short* Whb;     // [2560][512] bf16 (plain cached)
    const unsigned short* xgates;  // [T*B][2048] bf16 (plain cached)
    unsigned short* hbuf;          // [8][16][512] bf16 -- sc0sc1 exchanged
    float* Ybuf;                   // [8][2560][16] f32 -- sc0sc1 exchanged
    unsigned short* hallb;         // [T*B][512] bf16 (plain; next dispatch)
    float* attn;
    float* out_h;
    float* out_c;
    unsigned* hfl;                 // [128*32]
    unsigned* yfl;                 // [128*32]
};

// ---------------------------------------------------------------------------
// Persistent kernel: 128 blocks = 8 independent groups of 16 (grp=beta&7,
// slot=beta>>3). Group g owns batches [16g,16g+16). Per step:
//  P1: wait 16 hfl -> h_s (16x512, one 4-deep sc0sc1 load batch) ->
//      10 MFMA tiles for Y rows [slot*160, +160) (96 rows LDS weights,
//      64 streamed L2) -> Y col-major stores -> yfl.
//  P2: wait 4 qa yfl -> qa -> scores/softmax -> encW8 sum (prefetched
//      BEFORE gate wait) -> wait 16 yfl -> gates + xgates + LSTM -> hfl.
// Fan-in <=16 per wait; ~2MB/step of L3 exchange (vs r9's ~20MB).
// ---------------------------------------------------------------------------
__global__ __launch_bounds__(256, 1)
void persist(PParams p)
{
    __shared__ unsigned short WA[LROWS][520];
    __shared__ unsigned short h_s[16][520];
    __shared__ float qa_s[H];
    __shared__ float va_s[H];
    __shared__ float part[SS][4];
    __shared__ float wbuf[SS];
    __shared__ float gbuf[4 * H];
    __shared__ float cs[H];

    const int tid  = threadIdx.x;
    const int beta = blockIdx.x;
    const int grp  = beta & 7;
    const int slot = beta >> 3;
    const int gb   = grp * GSZ + slot;
    const int gi   = gb;
    const int wv   = tid >> 6, lane = tid & 63;
    const int fr   = lane & 15, fg = lane >> 4;

    unsigned short* hbg = p.hbuf + (size_t)grp * GSZ * H;
    float* ybg = p.Ybuf + (size_t)grp * 2560 * GSZ;

    // ---- prologue: stage weights, init per-batch state, publish h0 ----
    for (int idx = tid; idx < LROWS * 64; idx += 256) {
        const int r = idx >> 6, c = idx & 63;
        *(uint4*)&WA[r][c * 8] =
            *(const uint4*)&p.Whb[((size_t)slot * 160 + r) * H + c * 8];
    }
    for (int j = tid; j < H; j += 256) {
        cs[j] = p.c0[(size_t)gb * H + j];
        va_s[j] = p.Va[j];
    }
    {
        const float* hp = p.h0 + (size_t)gb * H;
        const unsigned hp32 = (unsigned)f2b(hp[tid * 2]) |
                              ((unsigned)f2b(hp[tid * 2 + 1]) << 16);
        cstu32c((unsigned*)(hbg + (size_t)slot * H) + tid, hp32);
    }
    __syncthreads();   // drain h0 stores (vmcnt 0) + LDS staging
    if (tid == 0) fst(&p.hfl[gi * 32], 1u);

    for (int t = 0; t < TT; ++t) {
        const unsigned st = (unsigned)(t + 1);
        // ---------------- P1 ----------------
        if (tid < GSZ) pollf(&p.hfl[(grp * GSZ + tid) * 32], st);
        __syncthreads();
        {   // h_s <- hbg (4 x 16B per thread, single wait)
            uint4 a, b, c4, d;
            cld4x16B(hbg + (size_t)tid * 8, hbg + (size_t)(tid + 256) * 8,
                     hbg + (size_t)(tid + 512) * 8, hbg + (size_t)(tid + 768) * 8,
                     a, b, c4, d);
            const int r0 = tid >> 6, c0 = (tid & 63) * 8;
            *(uint4*)&h_s[r0][c0]      = a;
            *(uint4*)&h_s[r0 + 4][c0]  = b;
            *(uint4*)&h_s[r0 + 8][c0]  = c4;
            *(uint4*)&h_s[r0 + 12][c0] = d;
        }
        __syncthreads();
        for (int tt = wv; tt < 10; tt += 4) {
            const int jrow = slot * 160 + tt * 16 + fr;
            f32x4 acc = {0.f, 0.f, 0.f, 0.f};
            if (tt < 6) {
#pragma unroll
                for (int ks = 0; ks < 16; ++ks) {
                    bf16x8 A = *(const bf16x8*)&h_s[fr][ks * 32 + fg * 8];
                    bf16x8 B = *(const bf16x8*)&WA[tt * 16 + fr][ks * 32 + fg * 8];
                    acc = __builtin_amdgcn_mfma_f32_16x16x32_bf16(A, B, acc, 0, 0, 0);
                }
            } else {
                const unsigned short* wr = p.Whb + (size_t)jrow * H;
#pragma unroll
                for (int ks = 0; ks < 16; ++ks) {
                    bf16x8 A = *(const bf16x8*)&h_s[fr][ks * 32 + fg * 8];
                    bf16x8 B = *(const bf16x8*)&wr[ks * 32 + fg * 8];
                    acc = __builtin_amdgcn_mfma_f32_16x16x32_bf16(A, B, acc, 0, 0, 0);
                }
            }
            const float bb = p.bbig[jrow];
            f32x4 o;
#pragma unroll
            for (int i = 0; i < 4; ++i) o[i] = acc[i] + bb;
            cstf4(ybg + (size_t)jrow * GSZ + fg * 4, o);
        }
        __syncthreads();   // drain Y stores
        if (tid == 0) fst(&p.yfl[gi * 32], st);

        // ---------------- P2 ----------------
        if (tid < 4) pollf(&p.yfl[(grp * GSZ + tid) * 32], st);   // qa rows 0-511
        __syncthreads();
        cldf2(ybg + (size_t)tid * GSZ + slot,
              ybg + (size_t)(tid + 256) * GSZ + slot,
              qa_s[tid], qa_s[tid + 256]);
        __syncthreads();
        {   // scores: vectorized keysb, 2-way ILP tanh chain
            const int s = tid >> 2, q = tid & 3;
            const unsigned short* kp = p.keysb + ((size_t)gb * SS + s) * H + q * 128;
            const float* qp = qa_s + q * 128;
            const float* vp = va_s + q * 128;
            float a2 = 0.f, a2b = 0.f;
#pragma unroll
            for (int i8 = 0; i8 < 16; ++i8) {
                bf16x8 kv = *(const bf16x8*)&kp[i8 * 8];
#pragma unroll
                for (int u = 0; u < 8; u += 2) {
                    const int i = i8 * 8 + u;
                    a2  += ftanh(qp[i]     + b2f((unsigned short)kv[u]))     * vp[i];
                    a2b += ftanh(qp[i + 1] + b2f((unsigned short)kv[u + 1])) * vp[i + 1];
                }
            }
            part[s][q] = a2 + a2b;
        }
        __syncthreads();
        if (tid < 64) {
            float sc = part[tid][0] + part[tid][1] + part[tid][2] + part[tid][3] + p.bv[0];
            float m = sc;
            for (int o = 32; o; o >>= 1) m = fmaxf(m, __shfl_xor(m, o));
            const float e = __expf(sc - m);
            float ss = e;
            for (int o = 32; o; o >>= 1) ss += __shfl_xor(ss, o);
            const float w = e / ss;
            wbuf[tid] = w;
            p.attn[((size_t)gb * TT + t) * SS + tid] = w;
        }
        __syncthreads();
        float gc[8] = {0.f, 0.f, 0.f, 0.f, 0.f, 0.f, 0.f, 0.f};
        {   // encW8 weighted sum FIRST (needs only wbuf) -> gate-producer slack
            const unsigned char* ew = p.encW8 + (size_t)gb * SS * 2048 + tid * 8;
#pragma unroll 8
            for (int s2 = 0; s2 < SS; ++s2) {
                const float w2 = wbuf[s2];
                const uint2 u = *(const uint2*)(ew + (size_t)s2 * 2048);
                const f32x2 e01 = __builtin_amdgcn_cvt_pk_f32_fp8(u.x, 0);
                const f32x2 e23 = __builtin_amdgcn_cvt_pk_f32_fp8(u.x, 1);
                const f32x2 e45 = __builtin_amdgcn_cvt_pk_f32_fp8(u.y, 0);
                const f32x2 e67 = __builtin_amdgcn_cvt_pk_f32_fp8(u.y, 1);
                gc[0] += w2 * e01[0]; gc[1] += w2 * e01[1];
                gc[2] += w2 * e23[0]; gc[3] += w2 * e23[1];
                gc[4] += w2 * e45[0]; gc[5] += w2 * e45[1];
                gc[6] += w2 * e67[0]; gc[7] += w2 * e67[1];
            }
        }
        if (tid < GSZ) pollf(&p.yfl[(grp * GSZ + tid) * 32], st);  // gate rows
        __syncthreads();
        {   // gates = gc + Y gate rows + xgates
            float yg[8];
            cldf8s(ybg + (size_t)(512 + tid * 8) * GSZ + slot, yg);
            bf16x8 xg = *(const bf16x8*)&p.xgates[((size_t)t * BB + gb) * 2048 + tid * 8];
#pragma unroll
            for (int i = 0; i < 8; ++i)
                gbuf[tid * 8 + i] = gc[i] + yg[i] + b2f((unsigned short)xg[i]);
        }
        __syncthreads();
        {   // LSTM: cells 2*tid, 2*tid+1
            const int last = (t == TT - 1);
            unsigned hpack = 0;
            float hn2[2], cn2[2];
#pragma unroll
            for (int u = 0; u < 2; ++u) {
                const int j = tid * 2 + u;
                const float ig  = gbuf[j];
                const float fgt = gbuf[512 + j];
                const float gg  = gbuf[1024 + j];
                const float og  = gbuf[1536 + j];
                const float co  = cs[j];
                const float cn = fsig(fgt) * co + fsig(ig) * ftanh(gg);
                const float hn = fsig(og) * ftanh(cn);
                cs[j] = cn;
                hn2[u] = hn; cn2[u] = cn;
                hpack |= ((unsigned)f2b(hn)) << (16 * u);
            }
            cstu32c((unsigned*)(hbg + (size_t)slot * H) + tid, hpack);
            *(unsigned*)&p.hallb[((size_t)t * BB + gb) * H + tid * 2] = hpack;
            if (last) {
#pragma unroll
                for (int u = 0; u < 2; ++u) {
                    p.out_h[gb * H + tid * 2 + u] = hn2[u];
                    p.out_c[gb * H + tid * 2 + u] = cn2[u];
                }
            }
        }
        __syncthreads();   // drain h stores
        if (tid == 0) fst(&p.hfl[gi * 32], st + 1);
    }
}

// ---------------------------------------------------------------------------
// In-place log-softmax over each row of 5000 logits.
// ---------------------------------------------------------------------------
__global__ __launch_bounds__(256)
void logsoftmax_rows(float* __restrict__ P)
{
    __shared__ float red[256];
    float* p = P + (size_t)blockIdx.x * V;
    const int tid = threadIdx.x;
    float m = -1e30f;
    for (int i = tid; i < V; i += 256) m = fmaxf(m, p[i]);
    red[tid] = m; __syncthreads();
    for (int sft = 128; sft; sft >>= 1) {
        if (tid < sft) red[tid] = fmaxf(red[tid], red[tid + sft]);
        __syncthreads();
    }
    m = red[0]; __syncthreads();
    float ssum = 0.f;
    for (int i = tid; i < V; i += 256) ssum += __expf(p[i] - m);
    red[tid] = ssum; __syncthreads();
    for (int sft = 128; sft; sft >>= 1) {
        if (tid < sft) red[tid] += red[tid + sft];
        __syncthreads();
    }
    const float lse = m + __logf(red[0]);
    for (int i = tid; i < V; i += 256) p[i] -= lse;
}

// ---------------------------------------------------------------------------
extern "C" void kernel_launch(void* const* d_in, const int* in_sizes, int n_in,
                              void* d_out, int out_size, void* d_ws, size_t ws_size,
                              hipStream_t stream)
{
    (void)in_sizes; (void)n_in; (void)out_size; (void)ws_size;
    const float* enc  = (const float*)d_in[0];
    const float* h0   = (const float*)d_in[1];
    const float* c0   = (const float*)d_in[2];
    const int*   tgt  = (const int*)  d_in[3];
    const float* emb  = (const float*)d_in[4];
    const float* Wa   = (const float*)d_in[5];
    const float* ba   = (const float*)d_in[6];
    const float* Ua   = (const float*)d_in[7];
    const float* bu   = (const float*)d_in[8];
    const float* Va   = (const float*)d_in[9];
    const float* bv   = (const float*)d_in[10];
    const float* Wih  = (const float*)d_in[11];
    const float* Whh  = (const float*)d_in[12];
    const float* bih  = (const float*)d_in[13];
    const float* bhh  = (const float*)d_in[14];
    const float* Wout = (const float*)d_in[15];
    const float* bout = (const float*)d_in[16];

    float* ws = (float*)d_ws;
    float* bbig = ws;                                      // 2,560 f32
    float* Ybuf = bbig + 2560;                             // 327,680 f32
    unsigned* flags = (unsigned*)(Ybuf + 327680);          // 8,192 u32
    unsigned* hfl = flags;                                 // 128*32
    unsigned* yfl = flags + 4096;                          // 128*32
    unsigned short* Whb   = (unsigned short*)(flags + 8192);   // 1,310,720 u16
    unsigned short* Wxb   = Whb + 1310720;                 // 1,048,576
    unsigned short* Wc    = Wxb + 1048576;                 // 1,048,576
    unsigned short* Uab   = Wc + 1048576;                  // 262,144
    unsigned short* Woutb = Uab + 262144;                  // 2,560,000
    unsigned short* encb  = Woutb + 2560000;               // 4,194,304
    unsigned short* keysb = encb + 4194304;                // 4,194,304
    unsigned short* xall  = keysb + 4194304;               // 3,407,872
    unsigned short* xgates= xall + 3407872;                // 13,631,488
    unsigned short* hallb = xgates + 13631488;             // 3,407,872
    unsigned short* hbuf  = hallb + 3407872;               // 65,536
    unsigned char*  encW8 = (unsigned char*)(hbuf + 65536); // 16,777,216 u8

    float* out    = (float*)d_out;
    float* out_h  = out + (size_t)BB * TT * V;
    float* out_c  = out_h + BB * H;
    float* out_at = out_c + BB * H;

    hipMemsetAsync(flags, 0, 8192 * sizeof(unsigned), stream);

    prep_w<<<dim3(2048), dim3(256), 0, stream>>>(
        Wa, Whh, Wih, ba, bih, bhh, Ua, Wout, enc,
        Whb, Wxb, Wc, Uab, Woutb, encb, bbig);
    gather_x<<<dim3(512), dim3(256), 0, stream>>>(emb, tgt, xall);

    // keys_proj = enc @ Ua^T + bu -> bf16 [8192,512]
    gemm_mfma<1, 0><<<dim3(4, 64), dim3(256), 0, stream>>>(
        encb, Uab, bu, nullptr, keysb, nullptr, BB * SS, H);
    // encW8 = enc @ Wc^T -> fp8 [8192,2048]
    gemm_mfma<2, 0><<<dim3(16, 64), dim3(256), 0, stream>>>(
        encb, Wc, nullptr, nullptr, nullptr, encW8, BB * SS, 2048);
    // xgates = x @ Wx^T -> bf16 [6656,2048]  (teacher-forced x-part, hoisted)
    gemm_mfma<1, 0><<<dim3(16, 52), dim3(256), 0, stream>>>(
        xall, Wxb, nullptr, nullptr, xgates, nullptr, TT * BB, 2048);

    PParams pp;
    pp.h0 = h0; pp.c0 = c0; pp.keysb = keysb; pp.encW8 = encW8;
    pp.Va = Va; pp.bv = bv; pp.bbig = bbig;
    pp.Whb = Whb; pp.xgates = xgates;
    pp.hbuf = hbuf; pp.Ybuf = Ybuf; pp.hallb = hallb;
    pp.attn = out_at; pp.out_h = out_h; pp.out_c = out_c;
    pp.hfl = hfl; pp.yfl = yfl;
    persist<<<dim3(NBLK), dim3(256), 0, stream>>>(pp);

    // logits: hallb[6656,512] @ Woutb^T + bout -> out[b,t,:], then log-softmax
    gemm_mfma<0, 1><<<dim3(40, 52), dim3(256), 0, stream>>>(
        hallb, Woutb, bout, out, nullptr, nullptr, TT * BB, V);
    logsoftmax_rows<<<dim3(BB * TT), dim3(256), 0, stream>>>(out);
}